// Round 9
// baseline (212.927 us; speedup 1.0000x reference)
//
#include <hip/hip_runtime.h>
#include <hip/hip_bf16.h>

#define BATCH 16
#define D_OUT 1024
#define D_HID 512
#define D_FLT 13824
#define N0Q 9216
#define TW 14
#define TH 14
#define NXT 19
#define NYT 19
#define NB 2

typedef __attribute__((ext_vector_type(8))) short bf16x8;
typedef __attribute__((ext_vector_type(4))) float f32x4;

__device__ __forceinline__ float lrelu(float x) { return x >= 0.f ? x : 0.2f * x; }
__device__ __forceinline__ ushort f2bf(float x) {
  unsigned u = __float_as_uint(x);
  u += 0x7FFFu + ((u >> 16) & 1u);
  return (ushort)(u >> 16);
}

// blocks [0,256): tex fp32 [32][256][256] -> bf16 pixel-major [256*256][32]
// blocks [256,2304): fc1  h1[b][j] = lrelu(z[b]·W1[j] + b1[j])
__global__ void fc1_tex_kernel(const float* __restrict__ z, const float* __restrict__ W1,
                               const float* __restrict__ b1, float* __restrict__ h1,
                               const float* __restrict__ tex, ushort* __restrict__ texT) {
  int tid = threadIdx.x;
  if (blockIdx.x < 256) {
    int p = blockIdx.x * 256 + tid;
    unsigned pk[16];
    #pragma unroll
    for (int i = 0; i < 16; ++i) {
      ushort lo = f2bf(tex[(2 * i) * 65536 + p]);
      ushort hi = f2bf(tex[(2 * i + 1) * 65536 + p]);
      pk[i] = (unsigned)lo | ((unsigned)hi << 16);
    }
    uint4* dst = (uint4*)&texT[(size_t)p * 32];
    #pragma unroll
    for (int qq = 0; qq < 4; ++qq) {
      uint4 v; v.x = pk[qq * 4]; v.y = pk[qq * 4 + 1]; v.z = pk[qq * 4 + 2]; v.w = pk[qq * 4 + 3];
      dst[qq] = v;
    }
    return;
  }
  int wid = ((blockIdx.x - 256) * 256 + tid) >> 6;
  int lane = tid & 63;
  int b = wid >> 9, j = wid & 511;
  float s = 0.f;
  for (int k = lane; k < D_OUT; k += 64) s += z[b * D_OUT + k] * W1[j * D_OUT + k];
  #pragma unroll
  for (int off = 32; off; off >>= 1) s += __shfl_xor(s, off);
  if (lane == 0) h1[b * 512 + j] = lrelu(s + b1[j]);
}

// fc2: h2[b][j] = lrelu(h1[b]·W2[j] + b2[j]); one wave per output.
__global__ void fc2_kernel(const float* __restrict__ in, const float* __restrict__ W,
                           const float* __restrict__ bias, float* __restrict__ out) {
  int wid = (blockIdx.x * blockDim.x + threadIdx.x) >> 6;
  int lane = threadIdx.x & 63;
  int b = wid >> 9, j = wid & 511;
  float s = 0.f;
  for (int k = lane; k < D_HID; k += 64) s += in[b * D_HID + k] * W[j * D_HID + k];
  #pragma unroll
  for (int off = 32; off; off >>= 1) s += __shfl_xor(s, off);
  if (lane == 0) out[b * 512 + j] = lrelu(s + bias[j]);
}

// fc3: wave per j, all 16 batches; writes bf16 filters PERMUTED to
// conv layout: flt0 -> [kpos][co32][ci32], flt1 -> 9216 + [kpos][co16][ci32].
__global__ void fc3_kernel(const float* __restrict__ h2, const float* __restrict__ W3,
                           const float* __restrict__ b3, ushort* __restrict__ wbf) {
  __shared__ float hs[BATCH * D_HID];
  int tid = threadIdx.x;
  for (int i = tid; i < BATCH * D_HID; i += 256) hs[i] = h2[i];
  __syncthreads();
  int w = tid >> 6, lane = tid & 63;
  int j = blockIdx.x * 4 + w;
  float acc[BATCH];
  #pragma unroll
  for (int b = 0; b < BATCH; ++b) acc[b] = 0.f;
  for (int k = lane; k < D_HID; k += 64) {
    float wv = W3[(size_t)j * D_HID + k];
    #pragma unroll
    for (int b = 0; b < BATCH; ++b) acc[b] += wv * hs[b * D_HID + k];
  }
  #pragma unroll
  for (int b = 0; b < BATCH; ++b) {
    #pragma unroll
    for (int off = 32; off; off >>= 1) acc[b] += __shfl_xor(acc[b], off);
  }
  if (lane == 0) {
    float bb = b3[j];
    int dst;
    if (j < N0Q) {
      int co = j / 288, rem = j - co * 288;
      int ci = rem / 9, kp = rem - ci * 9;
      dst = kp * 1024 + co * 32 + ci;
    } else {
      int t = j - N0Q;
      int co = t / 288, rem = t - co * 288;
      int ci = rem / 9, kp = rem - ci * 9;
      dst = N0Q + kp * 512 + co * 32 + ci;
    }
    #pragma unroll
    for (int b = 0; b < BATCH; ++b) wbf[(size_t)b * D_FLT + dst] = f2bf(acc[b] + bb);
  }
}

// Fused conv1(32->32,3x3,lrelu)+conv2(32->16,3x3) via MFMA 16x16x32 bf16.
// Block = 14x14 tile x NB=2 batches. LDS 37.25 KB -> 4 blocks/CU (16 waves:
// the R8 finding was per-wave pipe serialization with too few waves to
// overlap). conv1: 2 rows/iter = 4 interleaved MFMA chains; conv2: 4 chains.
__global__ __launch_bounds__(256, 4) void conv_mfma(const ushort* __restrict__ texT,
                                                    const ushort* __restrict__ wbf,
                                                    float* __restrict__ out) {
  extern __shared__ ushort sm[];
  ushort* texs  = sm;            // 18*18*32 = 10368 shorts
  ushort* inter = sm + 10368;    // 16*16*32 = 8192 + 64 pad
  const int tid = threadIdx.x;
  const int w = tid >> 6, lane = tid & 63;
  const int jn = lane & 15, q = lane >> 4;
  const int tx0 = blockIdx.x * TW, ty0 = blockIdx.y * TH;

  // tex tile (18 rows x 18 px) -> LDS (quad-swizzle j' = (j+(px>>1))&3), 0 outside
  for (int i = tid; i < 1296; i += 256) {
    int row = i / 72, c = i - row * 72;
    int px = c >> 2, j = c & 3;
    int gy = ty0 - 2 + row, gx = tx0 - 2 + px;
    int4 v; v.x = 0; v.y = 0; v.z = 0; v.w = 0;
    if (gy >= 0 && gy < 256 && gx >= 0 && gx < 256)
      v = ((const int4*)texT)[(gy * 256 + gx) * 4 + j];
    ((int4*)texs)[row * 72 + px * 4 + ((j + (px >> 1)) & 3)] = v;
  }
  __syncthreads();

  #pragma unroll 1
  for (int bb = 0; bb < NB; ++bb) {
    const int b = blockIdx.z * NB + bb;
    const ushort* wb = wbf + (size_t)b * D_FLT;

    // A-frags for this batch (contiguous 1KB/wave reads, L2-hot).
    bf16x8 a0[9][2];
    #pragma unroll
    for (int kp = 0; kp < 9; ++kp)
      #pragma unroll
      for (int h = 0; h < 2; ++h)
        a0[kp][h] = *(const bf16x8*)&wb[(kp * 32 + h * 16 + jn) * 32 + q * 8];
    bf16x8 a1[9];
    #pragma unroll
    for (int kp = 0; kp < 9; ++kp)
      a1[kp] = *(const bf16x8*)&wb[N0Q + (kp * 16 + jn) * 32 + q * 8];

    // protect inter while prev batch's conv2 still reads it (filter loads in flight)
    if (bb) __syncthreads();

    // conv1: 16 inter rows; wave w does (w, w+4) then (w+8, w+12): 4 chains/iter
    #pragma unroll
    for (int it = 0; it < 2; ++it) {
      int rA = w + 8 * it, rB = rA + 4;
      f32x4 aA0 = {0.f,0.f,0.f,0.f}, aA1 = {0.f,0.f,0.f,0.f};
      f32x4 aB0 = {0.f,0.f,0.f,0.f}, aB1 = {0.f,0.f,0.f,0.f};
      #pragma unroll
      for (int ky = 0; ky < 3; ++ky) {
        const ushort* tA = &texs[(rA + ky) * 576];
        const ushort* tB = &texs[(rB + ky) * 576];
        #pragma unroll
        for (int kx = 0; kx < 3; ++kx) {
          int p = jn + kx;
          int off = p * 32 + ((q + (p >> 1)) & 3) * 8;
          bf16x8 bfA = *(const bf16x8*)&tA[off];
          bf16x8 bfB = *(const bf16x8*)&tB[off];
          aA0 = __builtin_amdgcn_mfma_f32_16x16x32_bf16(a0[ky*3+kx][0], bfA, aA0, 0, 0, 0);
          aA1 = __builtin_amdgcn_mfma_f32_16x16x32_bf16(a0[ky*3+kx][1], bfA, aA1, 0, 0, 0);
          aB0 = __builtin_amdgcn_mfma_f32_16x16x32_bf16(a0[ky*3+kx][0], bfB, aB0, 0, 0, 0);
          aB1 = __builtin_amdgcn_mfma_f32_16x16x32_bf16(a0[ky*3+kx][1], bfB, aB1, 0, 0, 0);
        }
      }
      // D: col=lane&15 (pixel), row=(lane>>4)*4+reg (co). Out-of-image inter
      // positions must be EXACT ZERO (reference conv2 zero-pads).
      #pragma unroll
      for (int s2 = 0; s2 < 2; ++s2) {
        int r = s2 ? rB : rA;
        f32x4 c0 = s2 ? aB0 : aA0, c1 = s2 ? aB1 : aA1;
        int gy1 = ty0 - 1 + r, gx1 = tx0 - 1 + jn;
        bool inimg = (gy1 >= 0 && gy1 < 256 && gx1 >= 0 && gx1 < 256);
        ushort4 p0, p1;
        p0.x = f2bf(lrelu(c0[0])); p0.y = f2bf(lrelu(c0[1]));
        p0.z = f2bf(lrelu(c0[2])); p0.w = f2bf(lrelu(c0[3]));
        p1.x = f2bf(lrelu(c1[0])); p1.y = f2bf(lrelu(c1[1]));
        p1.z = f2bf(lrelu(c1[2])); p1.w = f2bf(lrelu(c1[3]));
        if (!inimg) {
          p0.x = p0.y = p0.z = p0.w = 0;
          p1.x = p1.y = p1.z = p1.w = 0;
        }
        int rec = r * 512 + jn * 32;
        int sub = (q & 1) * 4;
        *(ushort4*)&inter[rec + ((((q >> 1) + (jn >> 1)) & 3) * 8) + sub] = p0;
        *(ushort4*)&inter[rec + (((2 + (q >> 1) + (jn >> 1)) & 3) * 8) + sub] = p1;
      }
    }
    __syncthreads();

    // conv2: 14 output rows; wave w rows {w, w+4, w+8, w+12(<14)} = 4 chains
    // (rows >=14 recompute row 13, store-masked). Garbage lanes jn>=TW read
    // at worst into the 64-short pad and are store-masked.
    {
      int ro3 = w + 12;
      bool h4 = ro3 < TH;
      int r3 = h4 ? ro3 : 13;
      f32x4 c0 = {0.f,0.f,0.f,0.f}, c1 = {0.f,0.f,0.f,0.f};
      f32x4 c2 = {0.f,0.f,0.f,0.f}, c3 = {0.f,0.f,0.f,0.f};
      #pragma unroll
      for (int ky = 0; ky < 3; ++ky) {
        const ushort* i0 = &inter[(w + ky) * 512];
        const ushort* i1 = &inter[(w + 4 + ky) * 512];
        const ushort* i2 = &inter[(w + 8 + ky) * 512];
        const ushort* i3 = &inter[(r3 + ky) * 512];
        #pragma unroll
        for (int kx = 0; kx < 3; ++kx) {
          int p = jn + kx;
          int off = p * 32 + ((q + (p >> 1)) & 3) * 8;
          bf16x8 b0 = *(const bf16x8*)&i0[off];
          bf16x8 b1 = *(const bf16x8*)&i1[off];
          bf16x8 b2 = *(const bf16x8*)&i2[off];
          bf16x8 b3v = *(const bf16x8*)&i3[off];
          c0 = __builtin_amdgcn_mfma_f32_16x16x32_bf16(a1[ky*3+kx], b0, c0, 0, 0, 0);
          c1 = __builtin_amdgcn_mfma_f32_16x16x32_bf16(a1[ky*3+kx], b1, c1, 0, 0, 0);
          c2 = __builtin_amdgcn_mfma_f32_16x16x32_bf16(a1[ky*3+kx], b2, c2, 0, 0, 0);
          c3 = __builtin_amdgcn_mfma_f32_16x16x32_bf16(a1[ky*3+kx], b3v, c3, 0, 0, 0);
        }
      }
      int gx = tx0 + jn;
      if (jn < TW && gx < 256) {
        #pragma unroll
        for (int ci = 0; ci < 4; ++ci) {
          int co = q * 4 + ci;
          size_t base = ((size_t)b * 16 + co) * 256;
          int g0 = ty0 + w, g1 = ty0 + w + 4, g2 = ty0 + w + 8, g3 = ty0 + ro3;
          if (g0 < 256) out[(base + g0) * 256 + gx] = c0[ci];
          if (g1 < 256) out[(base + g1) * 256 + gx] = c1[ci];
          if (g2 < 256) out[(base + g2) * 256 + gx] = c2[ci];
          if (h4 && g3 < 256) out[(base + g3) * 256 + gx] = c3[ci];
        }
      }
    }
  }
}

extern "C" void kernel_launch(void* const* d_in, const int* in_sizes, int n_in,
                              void* d_out, int out_size, void* d_ws, size_t ws_size,
                              hipStream_t stream) {
  const float* z   = (const float*)d_in[0];
  const float* tex = (const float*)d_in[1];
  const float* W1  = (const float*)d_in[2];
  const float* b1  = (const float*)d_in[3];
  const float* W2  = (const float*)d_in[4];
  const float* b2  = (const float*)d_in[5];
  const float* W3  = (const float*)d_in[6];
  const float* b3  = (const float*)d_in[7];
  float* out = (float*)d_out;

  // ws layout (bytes): h1 [0,32768) | h2 [32768,65536) | wbf bf16 [65536,507904) | texT bf16 [507904,4702208)
  float*  h1   = (float*)d_ws;
  float*  h2   = (float*)((char*)d_ws + 32768);
  ushort* wbf  = (ushort*)((char*)d_ws + 65536);
  ushort* texT = (ushort*)((char*)d_ws + 507904);

  fc1_tex_kernel<<<2304, 256, 0, stream>>>(z, W1, b1, h1, tex, texT);
  fc2_kernel<<<2048, 256, 0, stream>>>(h1, W2, b2, h2);
  fc3_kernel<<<D_FLT / 4, 256, 0, stream>>>(h2, W3, b3, wbf);

  dim3 grid(NXT, NYT, BATCH / NB);
  conv_mfma<<<grid, 256, (10368 + 8192 + 64) * sizeof(ushort), stream>>>(texT, wbf, out);
}

// Round 10
// 106.498 us; speedup vs baseline: 1.9994x; 1.9994x over previous
//
#include <hip/hip_runtime.h>
#include <hip/hip_bf16.h>

#define BATCH 16
#define D_OUT 1024
#define D_HID 512
#define D_FLT 13824
#define N0Q 9216
#define TW 14
#define TH 16
#define NTX 19
#define NB 2

typedef __attribute__((ext_vector_type(8))) short bf16x8;
typedef __attribute__((ext_vector_type(4))) float f32x4;

__device__ __forceinline__ float lrelu(float x) { return x >= 0.f ? x : 0.2f * x; }
__device__ __forceinline__ ushort f2bf(float x) {
  unsigned u = __float_as_uint(x);
  u += 0x7FFFu + ((u >> 16) & 1u);
  return (ushort)(u >> 16);
}

// blocks [0,256): tex fp32 [32][256][256] -> bf16 pixel-major [256*256][32]
// blocks [256,2304): fc1  h1[b][j] = lrelu(z[b]·W1[j] + b1[j])
__global__ void fc1_tex_kernel(const float* __restrict__ z, const float* __restrict__ W1,
                               const float* __restrict__ b1, float* __restrict__ h1,
                               const float* __restrict__ tex, ushort* __restrict__ texT) {
  int tid = threadIdx.x;
  if (blockIdx.x < 256) {
    int p = blockIdx.x * 256 + tid;
    unsigned pk[16];
    #pragma unroll
    for (int i = 0; i < 16; ++i) {
      ushort lo = f2bf(tex[(2 * i) * 65536 + p]);
      ushort hi = f2bf(tex[(2 * i + 1) * 65536 + p]);
      pk[i] = (unsigned)lo | ((unsigned)hi << 16);
    }
    uint4* dst = (uint4*)&texT[(size_t)p * 32];
    #pragma unroll
    for (int qq = 0; qq < 4; ++qq) {
      uint4 v; v.x = pk[qq * 4]; v.y = pk[qq * 4 + 1]; v.z = pk[qq * 4 + 2]; v.w = pk[qq * 4 + 3];
      dst[qq] = v;
    }
    return;
  }
  int wid = ((blockIdx.x - 256) * 256 + tid) >> 6;
  int lane = tid & 63;
  int b = wid >> 9, j = wid & 511;
  float s = 0.f;
  for (int k = lane; k < D_OUT; k += 64) s += z[b * D_OUT + k] * W1[j * D_OUT + k];
  #pragma unroll
  for (int off = 32; off; off >>= 1) s += __shfl_xor(s, off);
  if (lane == 0) h1[b * 512 + j] = lrelu(s + b1[j]);
}

// fc2: h2[b][j] = lrelu(h1[b]·W2[j] + b2[j]); one wave per output.
__global__ void fc2_kernel(const float* __restrict__ in, const float* __restrict__ W,
                           const float* __restrict__ bias, float* __restrict__ out) {
  int wid = (blockIdx.x * blockDim.x + threadIdx.x) >> 6;
  int lane = threadIdx.x & 63;
  int b = wid >> 9, j = wid & 511;
  float s = 0.f;
  for (int k = lane; k < D_HID; k += 64) s += in[b * D_HID + k] * W[j * D_HID + k];
  #pragma unroll
  for (int off = 32; off; off >>= 1) s += __shfl_xor(s, off);
  if (lane == 0) out[b * 512 + j] = lrelu(s + bias[j]);
}

// fc3: wave per j, all 16 batches; writes bf16 filters PERMUTED to
// conv layout: flt0 -> [kpos][co32][ci32], flt1 -> 9216 + [kpos][co16][ci32].
__global__ void fc3_kernel(const float* __restrict__ h2, const float* __restrict__ W3,
                           const float* __restrict__ b3, ushort* __restrict__ wbf) {
  __shared__ float hs[BATCH * D_HID];
  int tid = threadIdx.x;
  for (int i = tid; i < BATCH * D_HID; i += 256) hs[i] = h2[i];
  __syncthreads();
  int w = tid >> 6, lane = tid & 63;
  int j = blockIdx.x * 4 + w;
  float acc[BATCH];
  #pragma unroll
  for (int b = 0; b < BATCH; ++b) acc[b] = 0.f;
  for (int k = lane; k < D_HID; k += 64) {
    float wv = W3[(size_t)j * D_HID + k];
    #pragma unroll
    for (int b = 0; b < BATCH; ++b) acc[b] += wv * hs[b * D_HID + k];
  }
  #pragma unroll
  for (int b = 0; b < BATCH; ++b) {
    #pragma unroll
    for (int off = 32; off; off >>= 1) acc[b] += __shfl_xor(acc[b], off);
  }
  if (lane == 0) {
    float bb = b3[j];
    int dst;
    if (j < N0Q) {
      int co = j / 288, rem = j - co * 288;
      int ci = rem / 9, kp = rem - ci * 9;
      dst = kp * 1024 + co * 32 + ci;
    } else {
      int t = j - N0Q;
      int co = t / 288, rem = t - co * 288;
      int ci = rem / 9, kp = rem - ci * 9;
      dst = N0Q + kp * 512 + co * 32 + ci;
    }
    #pragma unroll
    for (int b = 0; b < BATCH; ++b) wbf[(size_t)b * D_FLT + dst] = f2bf(acc[b] + bb);
  }
}

// Fused conv1(32->32,3x3,lrelu)+conv2(32->16,3x3), MFMA 16x16x32 bf16.
// Block = 14x16 tile x NB=2 batches. SLIDING-WINDOW rows: each wave owns
// consecutive rows; each staged LDS row is read ONCE (3 kx frags) and FMA'd
// into every chain whose 3x3 window covers it -> B-reads halved (612->312
// b128/block) and 10 (conv1) / 4 (conv2) independent MFMA chains for ILP.
__global__ __launch_bounds__(256, 3) void conv_mfma(const ushort* __restrict__ texT,
                                                    const ushort* __restrict__ wbf,
                                                    float* __restrict__ out) {
  extern __shared__ ushort sm[];
  ushort* texs  = sm;            // 20 rows x 18 px x 32 ci = 11520 shorts
  ushort* inter = sm + 11520;    // 18 x 16 x 32 = 9216 + 128 pad
  const int tid = threadIdx.x;
  const int w = tid >> 6, lane = tid & 63;
  const int jn = lane & 15, q = lane >> 4;
  const int tx0 = blockIdx.x * TW, ty0 = blockIdx.y * TH;

  // tex tile -> LDS (quad-swizzle j' = (j+(px>>1))&3), zero outside image
  for (int i = tid; i < 1440; i += 256) {
    int row = i / 72, c = i - row * 72;
    int px = c >> 2, j = c & 3;
    int gy = ty0 - 2 + row, gx = tx0 - 2 + px;
    int4 v; v.x = 0; v.y = 0; v.z = 0; v.w = 0;
    if (gy >= 0 && gy < 256 && gx >= 0 && gx < 256)
      v = ((const int4*)texT)[(gy * 256 + gx) * 4 + j];
    ((int4*)texs)[row * 72 + px * 4 + ((j + (px >> 1)) & 3)] = v;
  }
  __syncthreads();

  // conv1 row starts {0,5,9,13} (5 rows each, rows 9/13 duplicated -> same
  // values, benign); conv2 row starts 4w (4 rows each).
  const int s1 = 4 * w + (w > 0 ? 1 : 0);

  #pragma unroll 1
  for (int bb = 0; bb < NB; ++bb) {
    const int b = blockIdx.z * NB + bb;
    const ushort* wb = wbf + (size_t)b * D_FLT;

    // conv1 A-frags (contiguous 1KB/wave global reads, L2-hot)
    bf16x8 a0[9][2];
    #pragma unroll
    for (int kp = 0; kp < 9; ++kp)
      #pragma unroll
      for (int h = 0; h < 2; ++h)
        a0[kp][h] = *(const bf16x8*)&wb[(kp * 32 + h * 16 + jn) * 32 + q * 8];

    // protect inter while prev batch's conv2 still reads it
    if (bb) __syncthreads();

    // conv1 sliding window: 7 tex rows feed 5 output chains x 2 co-halves
    f32x4 acc[5][2];
    #pragma unroll
    for (int i = 0; i < 5; ++i) {
      acc[i][0] = f32x4{0.f, 0.f, 0.f, 0.f};
      acc[i][1] = f32x4{0.f, 0.f, 0.f, 0.f};
    }
    #pragma unroll
    for (int kyp = 0; kyp < 7; ++kyp) {
      const ushort* trow = &texs[(s1 + kyp) * 576];
      bf16x8 Bf[3];
      #pragma unroll
      for (int kx = 0; kx < 3; ++kx) {
        int p = jn + kx;
        Bf[kx] = *(const bf16x8*)&trow[p * 32 + ((q + (p >> 1)) & 3) * 8];
      }
      #pragma unroll
      for (int i = 0; i < 5; ++i) {
        int ky = kyp - i;
        if (ky >= 0 && ky < 3) {
          #pragma unroll
          for (int kx = 0; kx < 3; ++kx) {
            acc[i][0] = __builtin_amdgcn_mfma_f32_16x16x32_bf16(a0[ky * 3 + kx][0], Bf[kx], acc[i][0], 0, 0, 0);
            acc[i][1] = __builtin_amdgcn_mfma_f32_16x16x32_bf16(a0[ky * 3 + kx][1], Bf[kx], acc[i][1], 0, 0, 0);
          }
        }
      }
    }
    // D: col=lane&15 (pixel), row=(lane>>4)*4+reg (co). Out-of-image inter
    // positions must be EXACT ZERO (reference conv2 zero-pads).
    #pragma unroll
    for (int i = 0; i < 5; ++i) {
      int r = s1 + i;
      int gy1 = ty0 - 1 + r, gx1 = tx0 - 1 + jn;
      bool inimg = (gy1 >= 0 && gy1 < 256 && gx1 >= 0 && gx1 < 256);
      ushort4 p0, p1;
      p0.x = f2bf(lrelu(acc[i][0][0])); p0.y = f2bf(lrelu(acc[i][0][1]));
      p0.z = f2bf(lrelu(acc[i][0][2])); p0.w = f2bf(lrelu(acc[i][0][3]));
      p1.x = f2bf(lrelu(acc[i][1][0])); p1.y = f2bf(lrelu(acc[i][1][1]));
      p1.z = f2bf(lrelu(acc[i][1][2])); p1.w = f2bf(lrelu(acc[i][1][3]));
      if (!inimg) {
        p0.x = p0.y = p0.z = p0.w = 0;
        p1.x = p1.y = p1.z = p1.w = 0;
      }
      int rec = r * 512 + jn * 32;
      int sub = (q & 1) * 4;
      *(ushort4*)&inter[rec + ((((q >> 1) + (jn >> 1)) & 3) * 8) + sub] = p0;
      *(ushort4*)&inter[rec + (((2 + (q >> 1) + (jn >> 1)) & 3) * 8) + sub] = p1;
    }

    // conv2 A-frags loaded HERE (not earlier) to keep conv1 reg peak <=168;
    // sched_barrier stops the compiler hoisting them above conv1.
    __builtin_amdgcn_sched_barrier(0);
    bf16x8 a1[9];
    #pragma unroll
    for (int kp = 0; kp < 9; ++kp)
      a1[kp] = *(const bf16x8*)&wb[N0Q + (kp * 16 + jn) * 32 + q * 8];
    __syncthreads();

    // conv2 sliding window: 6 inter rows feed 4 output chains; garbage lanes
    // (jn>=TW) read at worst into the 128-short pad and are store-masked.
    {
      const int s2 = 4 * w;
      f32x4 c[4];
      #pragma unroll
      for (int i = 0; i < 4; ++i) c[i] = f32x4{0.f, 0.f, 0.f, 0.f};
      #pragma unroll
      for (int kyp = 0; kyp < 6; ++kyp) {
        const ushort* irow = &inter[(s2 + kyp) * 512];
        bf16x8 Bf[3];
        #pragma unroll
        for (int kx = 0; kx < 3; ++kx) {
          int p = jn + kx;
          Bf[kx] = *(const bf16x8*)&irow[p * 32 + ((q + (p >> 1)) & 3) * 8];
        }
        #pragma unroll
        for (int i = 0; i < 4; ++i) {
          int ky = kyp - i;
          if (ky >= 0 && ky < 3) {
            #pragma unroll
            for (int kx = 0; kx < 3; ++kx)
              c[i] = __builtin_amdgcn_mfma_f32_16x16x32_bf16(a1[ky * 3 + kx], Bf[kx], c[i], 0, 0, 0);
          }
        }
      }
      int gx = tx0 + jn;
      if (jn < TW && gx < 256) {
        #pragma unroll
        for (int i = 0; i < 4; ++i) {
          int gy = ty0 + s2 + i;
          #pragma unroll
          for (int ci = 0; ci < 4; ++ci) {
            int co = q * 4 + ci;
            out[(((size_t)b * 16 + co) * 256 + gy) * 256 + gx] = c[i][ci];
          }
        }
      }
    }
  }
}

extern "C" void kernel_launch(void* const* d_in, const int* in_sizes, int n_in,
                              void* d_out, int out_size, void* d_ws, size_t ws_size,
                              hipStream_t stream) {
  const float* z   = (const float*)d_in[0];
  const float* tex = (const float*)d_in[1];
  const float* W1  = (const float*)d_in[2];
  const float* b1  = (const float*)d_in[3];
  const float* W2  = (const float*)d_in[4];
  const float* b2  = (const float*)d_in[5];
  const float* W3  = (const float*)d_in[6];
  const float* b3  = (const float*)d_in[7];
  float* out = (float*)d_out;

  // ws layout (bytes): h1 [0,32768) | h2 [32768,65536) | wbf bf16 [65536,507904) | texT bf16 [507904,4702208)
  float*  h1   = (float*)d_ws;
  float*  h2   = (float*)((char*)d_ws + 32768);
  ushort* wbf  = (ushort*)((char*)d_ws + 65536);
  ushort* texT = (ushort*)((char*)d_ws + 507904);

  fc1_tex_kernel<<<2304, 256, 0, stream>>>(z, W1, b1, h1, tex, texT);
  fc2_kernel<<<2048, 256, 0, stream>>>(h1, W2, b2, h2);
  fc3_kernel<<<D_FLT / 4, 256, 0, stream>>>(h2, W3, b3, wbf);

  dim3 grid(NTX, 256 / TH, BATCH / NB);
  conv_mfma<<<grid, 256, (11520 + 9216 + 128) * sizeof(ushort), stream>>>(texT, wbf, out);
}